// Round 19
// baseline (74.040 us; speedup 1.0000x reference)
//
#include <hip/hip_runtime.h>
#include <hip/hip_bf16.h>
#include <math.h>

#define BB 8
#define NN 1024
#define F_IN 384
#define F_HID 96
#define HEADS 8
#define F_OUT 384
#define ROWS (BB*NN)                 // 8192
#define H_DIM 1152                   // HEADS*F_HID + F_IN
#define OUT_DIM 1536                 // F_OUT + H_DIM
#define NEG 0.01f
#define LN_EPS 1e-5f
#define LOG2E 1.4426950408889634f

typedef __bf16 bf16x8 __attribute__((ext_vector_type(8)));
typedef float  f32x4  __attribute__((ext_vector_type(4)));

static __device__ __forceinline__ unsigned short b16u(float x) {
    union { __bf16 h; unsigned short u; } c; c.h = (__bf16)x; return c.u;
}
static __device__ __forceinline__ unsigned int pk2(float lo, float hi) {
    return (unsigned int)b16u(lo) | ((unsigned int)b16u(hi) << 16);
}

typedef __attribute__((address_space(1))) const unsigned char g1_t;
typedef __attribute__((address_space(3))) unsigned char l3_t;
static __device__ __forceinline__ void gl16(const void* g, void* l) {
    __builtin_amdgcn_global_load_lds((g1_t*)g, (l3_t*)l, 16, 0, 0);
}

// ---------------- kW: WmT[n][k] = bf16(Wm[k][n]) ; WvT[f][k] = bf16(Wv[k][f]) ----
__global__ __launch_bounds__(256) void kW(const float* __restrict__ Wm,
                                          const float* __restrict__ Wv,
                                          unsigned short* __restrict__ WmT,
                                          unsigned short* __restrict__ WvT) {
    __shared__ float tile[32][33];
    const int t = threadIdx.x;
    const int bid = (int)blockIdx.x;
    const float* src; unsigned short* dst;
    int k0, n0, srcld, dstld;
    if (bid < 432) {
        k0 = (bid / 12) * 32; n0 = (bid % 12) * 32;
        src = Wm; dst = WmT; srcld = F_OUT; dstld = H_DIM;
    } else {
        const int e = bid - 432;
        k0 = (e / 3) * 32; n0 = (e % 3) * 32;
        src = Wv; dst = WvT; srcld = F_HID; dstld = F_IN;
    }
#pragma unroll
    for (int p = 0; p < 4; ++p) {
        const int e = t + 256*p, kk = e >> 5, nn = e & 31;
        tile[kk][nn] = src[(size_t)(k0 + kk) * srcld + n0 + nn];
    }
    __syncthreads();
#pragma unroll
    for (int p = 0; p < 4; ++p) {
        const int e = t + 256*p, nn = e >> 5, kk = e & 31;
        dst[(size_t)(n0 + nn) * dstld + k0 + kk] = b16u(tile[kk][nn]);
    }
}

// ---------------- kA: fused LN(X) -> bf16 (LDS) -> V = MFMA -> VT, Q, K ------------
// [PROVEN R12/R16] + X passthrough write + NEW: XS[row] = {Sum x, Sum x^2} for kB
__global__ __launch_bounds__(384) void kA(const float* __restrict__ X,
                                          const unsigned short* __restrict__ WvT,
                                          const float* __restrict__ bv,
                                          const float* __restrict__ Wq, const float* __restrict__ bq,
                                          const float* __restrict__ Wk, const float* __restrict__ bk,
                                          unsigned short* __restrict__ VT,
                                          float* __restrict__ Qw, float* __restrict__ Kw,
                                          float* __restrict__ out,
                                          float2* __restrict__ XS) {
    __shared__ __align__(16) unsigned short xn[16][392];
    __shared__ float vsh[96][17];
    const int t = threadIdx.x;
    const int bid = (int)blockIdx.x;
    const int swz = (bid & 7) * 64 + (bid >> 3);
    const int i0 = swz * 16;
    const int b = i0 >> 10, i_in = i0 & 1023;
    const int w = t >> 6, l = t & 63, m = l & 15, g = l >> 4;

    if (t < 256) {
        const int r = t >> 4, l16 = t & 15;
        const float4* xrow = (const float4*)(X + (size_t)(i0 + r) * F_IN);
        float4* oX = (float4*)(out + (size_t)(i0 + r) * OUT_DIM + F_OUT + HEADS*F_HID);
        float4 xv[6];
        float s = 0.f, sq = 0.f;
#pragma unroll
        for (int k = 0; k < 6; ++k) {
            xv[k] = xrow[l16 + 16*k];
            oX[l16 + 16*k] = xv[k];
            s  += xv[k].x + xv[k].y + xv[k].z + xv[k].w;
            sq += xv[k].x*xv[k].x + xv[k].y*xv[k].y + xv[k].z*xv[k].z + xv[k].w*xv[k].w;
        }
#pragma unroll
        for (int msk = 1; msk < 16; msk <<= 1) { s += __shfl_xor(s, msk); sq += __shfl_xor(sq, msk); }
        if (l16 == 0) XS[(size_t)(i0 + r)] = make_float2(s, sq);   // raw-X row sums for kB
        const float mu  = s * (1.f/F_IN);
        const float var = sq * (1.f/F_IN) - mu*mu;
        const float rstd = rsqrtf(var + LN_EPS);
#pragma unroll
        for (int k = 0; k < 6; ++k) {
            ushort4 h4;
            h4.x = b16u((xv[k].x - mu) * rstd);
            h4.y = b16u((xv[k].y - mu) * rstd);
            h4.z = b16u((xv[k].z - mu) * rstd);
            h4.w = b16u((xv[k].w - mu) * rstd);
            *(ushort4*)&xn[r][4*(l16 + 16*k)] = h4;
        }
    }
    __syncthreads();

    const f32x4 z4 = {0.f, 0.f, 0.f, 0.f};
    f32x4 acc = z4;
    const unsigned short* Br = WvT + (size_t)(w*16 + m) * F_IN + g*8;
#pragma unroll
    for (int ks = 0; ks < 12; ++ks) {
        const bf16x8 af  = *(const bf16x8*)&xn[m][ks*32 + g*8];
        const bf16x8 bfr = *(const bf16x8*)(Br + ks*32);
        acc = __builtin_amdgcn_mfma_f32_16x16x32_bf16(af, bfr, acc, 0, 0, 0);
    }
    {
        const int f = w*16 + m;
        const float bvv = bv[f];
#pragma unroll
        for (int r = 0; r < 4; ++r)
            vsh[f][g*4 + r] = acc[r] + bvv;
    }
    __syncthreads();

    {
        const int f = t >> 2, ic = (t & 3) * 4;
        ushort4 h4;
        h4.x = b16u(vsh[f][ic]);   h4.y = b16u(vsh[f][ic+1]);
        h4.z = b16u(vsh[f][ic+2]); h4.w = b16u(vsh[f][ic+3]);
        *(ushort4*)&VT[((size_t)b * F_HID + f) * NN + i_in + ic] = h4;
    }

    if (t < 256) {
        const int i_loc = t & 15, h = (t >> 4) & 7;
        const bool isQ = (t < 128);
        const float* Wx = isQ ? Wq : Wk;
        float a = isQ ? bq[h] : bk[h];
#pragma unroll 8
        for (int f = 0; f < F_HID; ++f)
            a = fmaf(vsh[f][i_loc], Wx[f*HEADS + h], a);
        if (isQ) Qw[(size_t)(i0 + i_loc) * HEADS + h] = a;
        else     Kw[(size_t)(i0 + i_loc) * HEADS + h] = a;
    }
}

// ---------------- kB: 8-wave MFMA attention + fused LN(H) [R18 base] ---------------
// Changes vs R18: (1) X row sums read from XS (kA precomputed; exact) -- the 512-thread
// X reduction + sxS/sx2S round-trip deleted; X read once in epilogue for Hn write.
// (2) #pragma unroll 2 on main loop (cur/nxt become compile-time).
__global__ __launch_bounds__(512, 4) void kB(const float* __restrict__ X,
                                             const unsigned short* __restrict__ VT,
                                             const float* __restrict__ Qw,
                                             const float* __restrict__ Kw,
                                             const float2* __restrict__ XS,
                                             float* __restrict__ out,
                                             unsigned short* __restrict__ Hn) {
    __shared__ float q_sh[16][8];
    __shared__ __align__(16) unsigned short Wt[2][HEADS][16][64];   // 32 KB (swizzled)
    __shared__ __align__(16) unsigned short vt_sh[2][F_HID][64];    // 24 KB (swizzled)
    __shared__ float lnS[8][16], lnQ2[8][16];
    __shared__ float mu_sh[16], rs_sh[16];

    const int t = threadIdx.x;
    const int bid = (int)blockIdx.x;
    const int swz = (bid & 7) * 64 + (bid >> 3);   // bijective XCD swizzle (512%8==0)
    const int b  = swz >> 6;
    const int i0 = (swz & 63) * 16;
    const int w = t >> 6, l = t & 63, m = l & 15, g = l >> 4;
    const int hp = w >> 1, fh = w & 1;
    const int si = t >> 5, jd = t & 31;

    if (t < 128) ((float*)q_sh)[t] = Qw[((size_t)(b*NN + i0)) * HEADS + t];

    const f32x4 z4 = {0.f, 0.f, 0.f, 0.f};
    f32x4 acc[2][3];
#pragma unroll
    for (int h2 = 0; h2 < 2; ++h2)
#pragma unroll
        for (int fb = 0; fb < 3; ++fb) acc[h2][fb] = z4;

    const size_t vtbase = (size_t)b * F_HID * NN;
    const size_t krow   = (size_t)b * NN;

    // softmax for j-chunk at jbase -> Wt[db]; K direct from global (L1-resident)
#define SMAX(jbase, db)                                                                \
    {                                                                                  \
        const float* kp = Kw + (krow + (jbase) + 2*jd) * HEADS;                        \
        const float4 ka0 = *(const float4*)(kp);                                       \
        const float4 ka1 = *(const float4*)(kp + 4);                                   \
        const float4 kb0 = *(const float4*)(kp + 8);                                   \
        const float4 kb1 = *(const float4*)(kp + 12);                                  \
        const float kE[8] = {ka0.x,ka0.y,ka0.z,ka0.w, ka1.x,ka1.y,ka1.z,ka1.w};        \
        const float kO[8] = {kb0.x,kb0.y,kb0.z,kb0.w, kb1.x,kb1.y,kb1.z,kb1.w};        \
        float p0[8], p1[8];                                                            \
        float s0 = 0.f, s1 = 0.f;                                                      \
        _Pragma("unroll")                                                              \
        for (int h = 0; h < 8; ++h) {                                                  \
            float a0 = q[h] * kE[h]; a0 = fmaxf(a0, NEG*a0);                           \
            float a1 = q[h] * kO[h]; a1 = fmaxf(a1, NEG*a1);                           \
            p0[h] = __builtin_amdgcn_exp2f(a0); s0 += p0[h];                           \
            p1[h] = __builtin_amdgcn_exp2f(a1); s1 += p1[h];                           \
        }                                                                              \
        const float inv0 = 1.f / s0, inv1 = 1.f / s1;                                  \
        char* wbase = (char*)Wt + (db)*16384 + si*128                                  \
                    + ((((jd>>2) ^ (si & 7))) << 4) + ((jd & 3) << 2);                 \
        _Pragma("unroll")                                                              \
        for (int h = 0; h < 8; ++h)                                                    \
            *(unsigned int*)(wbase + h*2048) = pk2(p0[h]*inv0, p1[h]*inv1);            \
    }

    // prologue: stage V(0)
    {
        uint4 vr0, vr1;
        {
            const int f = t >> 3, u = t & 7;
            vr0 = *(const uint4*)(VT + vtbase + (size_t)f*NN + u*8);
        }
        if (t < 256) {
            const int e = t + 512, f2 = e >> 3, u2 = e & 7;
            vr1 = *(const uint4*)(VT + vtbase + (size_t)f2*NN + u2*8);
        }
        {
            const int f = t >> 3, u = t & 7;
            *(uint4*)((char*)vt_sh + f*128 + ((u ^ (f & 7)) << 4)) = vr0;
        }
        if (t < 256) {
            const int e = t + 512, f2 = e >> 3, u2 = e & 7;
            *(uint4*)((char*)vt_sh + f2*128 + ((u2 ^ (f2 & 7)) << 4)) = vr1;
        }
    }
    __syncthreads();

    float q[8];
#pragma unroll
    for (int h = 0; h < 8; ++h) q[h] = q_sh[si][h] * LOG2E;

    SMAX(0, 0);
    __syncthreads();

#pragma unroll 2
    for (int c = 0; c < 16; ++c) {
        const int cur = c & 1, nxt = cur ^ 1;

        // phase A: issue next-chunk V reg loads
        uint4 vr0, vr1;
        if (c < 15) {
            const int j0n = (c + 1) * 64;
            {
                const int f = t >> 3, u = t & 7;
                vr0 = *(const uint4*)(VT + vtbase + (size_t)f*NN + j0n + u*8);
            }
            if (t < 256) {
                const int e = t + 512, f2 = e >> 3, u2 = e & 7;
                vr1 = *(const uint4*)(VT + vtbase + (size_t)f2*NN + j0n + u2*8);
            }
        }

        // phase B: softmax(c+1) -> Wt[nxt] (K direct from global)
        if (c < 15) SMAX((c + 1) * 64, nxt);

        // phase C: MFMA chunk c
        __builtin_amdgcn_s_setprio(1);
#pragma unroll
        for (int kh = 0; kh < 2; ++kh) {
            const int swzu = ((kh*4 + g) ^ (m & 7)) << 4;
            bf16x8 af[2];
#pragma unroll
            for (int h2 = 0; h2 < 2; ++h2)
                af[h2] = *(const bf16x8*)((const char*)Wt + cur*16384
                                          + (hp*2 + h2)*2048 + m*128 + swzu);
            bf16x8 bfr[3];
#pragma unroll
            for (int fb = 0; fb < 3; ++fb) {
                const int f = fh*48 + fb*16 + m;
                bfr[fb] = *(const bf16x8*)((const char*)vt_sh + cur*12288 + f*128 + swzu);
            }
#pragma unroll
            for (int h2 = 0; h2 < 2; ++h2)
#pragma unroll
                for (int fb = 0; fb < 3; ++fb)
                    acc[h2][fb] = __builtin_amdgcn_mfma_f32_16x16x32_bf16(
                        af[h2], bfr[fb], acc[h2][fb], 0, 0, 0);
        }
        __builtin_amdgcn_s_setprio(0);

        // phase D: write staged V regs -> vt_sh[nxt]
        if (c < 15) {
            {
                const int f = t >> 3, u = t & 7;
                *(uint4*)((char*)vt_sh + nxt*12288 + f*128 + ((u ^ (f & 7)) << 4)) = vr0;
            }
            if (t < 256) {
                const int e = t + 512, f2 = e >> 3, u2 = e & 7;
                *(uint4*)((char*)vt_sh + nxt*12288 + f2*128 + ((u2 ^ (f2 & 7)) << 4)) = vr1;
            }
        }
        __syncthreads();   // single barrier: publishes Wt[nxt], vt[nxt]
    }
#undef SMAX

    // ---- fused LN(H): per-row Hh sums from accs; X sums from XS (kA precomputed) ----
    float s[4] = {0,0,0,0}, s2[4] = {0,0,0,0};
#pragma unroll
    for (int h2 = 0; h2 < 2; ++h2)
#pragma unroll
        for (int fb = 0; fb < 3; ++fb)
#pragma unroll
            for (int r = 0; r < 4; ++r) {
                const float v = acc[h2][fb][r];
                s[r] += v; s2[r] += v*v;
            }
#pragma unroll
    for (int msk = 1; msk < 16; msk <<= 1)
#pragma unroll
        for (int r = 0; r < 4; ++r) {
            s[r]  += __shfl_xor(s[r],  msk);
            s2[r] += __shfl_xor(s2[r], msk);
        }
    if (m == 0) {
#pragma unroll
        for (int r = 0; r < 4; ++r) { lnS[w][g*4+r] = s[r]; lnQ2[w][g*4+r] = s2[r]; }
    }
    __syncthreads();

    if (t < 16) {
        const float2 xsum = XS[(size_t)(b*NN + i0) + t];
        float tot = xsum.x, tot2 = xsum.y;
#pragma unroll
        for (int ww = 0; ww < 8; ++ww) { tot += lnS[ww][t]; tot2 += lnQ2[ww][t]; }
        const float muh = tot * (1.f/H_DIM);
        const float varh = tot2 * (1.f/H_DIM) - muh*muh;
        mu_sh[t] = muh; rs_sh[t] = rsqrtf(varh + LN_EPS);
    }
    __syncthreads();

    // Hh: fp32 to out cols [384..1152), bf16-normalized to Hn cols [0..768)
#pragma unroll
    for (int r = 0; r < 4; ++r) {
        const int row = g*4 + r;
        const size_t orow = (size_t)(b*NN + i0 + row);
        const float muh = mu_sh[row], rs = rs_sh[row];
#pragma unroll
        for (int h2 = 0; h2 < 2; ++h2)
#pragma unroll
            for (int fb = 0; fb < 3; ++fb) {
                const int col = (hp*2 + h2)*F_HID + fh*48 + fb*16 + m;
                const float v = acc[h2][fb][r];
                out[orow * OUT_DIM + F_OUT + col] = v;
                Hn[orow * H_DIM + col] = b16u((v - muh) * rs);
            }
    }
    // normalized X -> Hn cols [768..1152) (X read once here)
    {
        const int rX = t >> 5, lX = t & 31;
        const size_t xrow = (size_t)(b*NN + i0 + rX);
        const float4* x4 = (const float4*)(X + xrow * F_IN);
        const float muh = mu_sh[rX], rs = rs_sh[rX];
#pragma unroll
        for (int kk = 0; kk < 3; ++kk) {
            const float4 xv = x4[lX + 32*kk];
            ushort4 hh;
            hh.x = b16u((xv.x - muh) * rs);
            hh.y = b16u((xv.y - muh) * rs);
            hh.z = b16u((xv.z - muh) * rs);
            hh.w = b16u((xv.w - muh) * rs);
            *(ushort4*)&Hn[xrow * H_DIM + HEADS*F_HID + 4*(lX + 32*kk)] = hh;
        }
    }
}

// ---------------- kC: O = lrelu(Hn @ WmT^T + bm), BM=64 BN=48, grid 1024 [PROVEN R12] ----
__global__ __launch_bounds__(256) void kC(const unsigned short* __restrict__ Hn,
                                          const unsigned short* __restrict__ WmT,
                                          const float* __restrict__ bm,
                                          float* __restrict__ out) {
    __shared__ __align__(16) unsigned short As[2][64*64];
    __shared__ __align__(16) unsigned short Bs[2][48*64];
    const int t = threadIdx.x, w = t >> 6, lane = t & 63, m = lane & 15, g = lane >> 4;
    const int bid = (int)blockIdx.x;
    const int swz = (bid & 7) * 128 + (bid >> 3);
    const int i0 = (swz >> 3) * 64;
    const int n0 = (swz & 7) * 48;

    const f32x4 z4 = {0.f, 0.f, 0.f, 0.f};
    f32x4 acc[3];
#pragma unroll
    for (int ns = 0; ns < 3; ++ns) acc[ns] = z4;

#define KC_STAGE(buf, k0)                                                              \
    {                                                                                  \
        _Pragma("unroll")                                                              \
        for (int p = 0; p < 2; ++p) {                                                  \
            const int e = t + 256*p, row = e >> 3, c16 = e & 7;                        \
            gl16(Hn + (size_t)(i0+row)*H_DIM + (k0) + ((c16 ^ (row&7)) << 3),          \
                 (char*)As[buf] + e*16);                                               \
        }                                                                              \
        {                                                                              \
            const int row = t >> 3, c16 = t & 7;                                       \
            gl16(WmT + (size_t)(n0+row)*H_DIM + (k0) + ((c16 ^ (row&7)) << 3),         \
                 (char*)Bs[buf] + t*16);                                               \
        }                                                                              \
        if (t < 128) {                                                                 \
            const int e = t + 256, row = e >> 3, c16 = e & 7;                          \
            gl16(WmT + (size_t)(n0+row)*H_DIM + (k0) + ((c16 ^ (row&7)) << 3),         \
                 (char*)Bs[buf] + e*16);                                               \
        }                                                                              \
    }

    KC_STAGE(0, 0);
    __syncthreads();

    for (int s = 0; s < 18; ++s) {
        const int cur = s & 1;
        if (s < 17) KC_STAGE(cur ^ 1, (s + 1) * 64);
#pragma unroll
        for (int kh = 0; kh < 2; ++kh) {
            const int kb = kh*64 + g*16;
            const int rowA = w*16 + m;
            const bf16x8 af = *(const bf16x8*)((const char*)As[cur] + rowA*128
                                               + (kb ^ ((rowA&7)<<4)));
#pragma unroll
            for (int ns = 0; ns < 3; ++ns) {
                const int row = ns*16 + m;
                const bf16x8 bf_ = *(const bf16x8*)((const char*)Bs[cur] + row*128
                                                    + (kb ^ ((row&7)<<4)));
                acc[ns] = __builtin_amdgcn_mfma_f32_16x16x32_bf16(af, bf_, acc[ns], 0, 0, 0);
            }
        }
        __syncthreads();
    }
#undef KC_STAGE

#pragma unroll
    for (int ns = 0; ns < 3; ++ns) {
        const int col = n0 + ns*16 + m;
        const float bmv = bm[col];
#pragma unroll
        for (int r = 0; r < 4; ++r) {
            float o = acc[ns][r] + bmv;
            o = fmaxf(o, NEG * o);
            out[(size_t)(i0 + w*16 + g*4 + r) * OUT_DIM + col] = o;
        }
    }
}

extern "C" void kernel_launch(void* const* d_in, const int* in_sizes, int n_in,
                              void* d_out, int out_size, void* d_ws, size_t ws_size,
                              hipStream_t stream) {
    const float* X  = (const float*)d_in[0];
    const float* Wv = (const float*)d_in[1];
    const float* bv = (const float*)d_in[2];
    const float* Wq = (const float*)d_in[3];
    const float* bq = (const float*)d_in[4];
    const float* Wk = (const float*)d_in[5];
    const float* bk = (const float*)d_in[6];
    const float* Wm = (const float*)d_in[7];
    const float* bm = (const float*)d_in[8];
    float* out = (float*)d_out;

    char* p = (char*)d_ws;
    unsigned short* VT  = (unsigned short*)p;                 p += (size_t)BB*F_HID*NN*2;
    float*          Qw  = (float*)p;                          p += (size_t)ROWS*HEADS*4;
    float*          Kw  = (float*)p;                          p += (size_t)ROWS*HEADS*4;
    unsigned short* WmT = (unsigned short*)p;                 p += (size_t)F_OUT*H_DIM*2;
    unsigned short* WvT = (unsigned short*)p;                 p += (size_t)F_HID*F_IN*2;
    float2*         XS  = (float2*)p;                         p += (size_t)ROWS*8;
    unsigned short* Hn  = (unsigned short*)p;                 // ROWS*H_DIM*2 = 18 MB
    (void)ws_size; (void)out_size; (void)n_in; (void)in_sizes;

    kW<<<468, 256, 0, stream>>>(Wm, Wv, WmT, WvT);
    kA<<<ROWS/16, 384, 0, stream>>>(X, WvT, bv, Wq, bq, Wk, bk, VT, Qw, Kw, out, XS);
    kB<<<BB*(NN/16), 512, 0, stream>>>(X, VT, Qw, Kw, XS, out, Hn);
    kC<<<(ROWS/64)*(F_OUT/48), 256, 0, stream>>>(Hn, WmT, bm, out);
}

// Round 20
// 70.847 us; speedup vs baseline: 1.0451x; 1.0451x over previous
//
#include <hip/hip_runtime.h>
#include <hip/hip_bf16.h>
#include <math.h>

#define BB 8
#define NN 1024
#define F_IN 384
#define F_HID 96
#define HEADS 8
#define F_OUT 384
#define ROWS (BB*NN)                 // 8192
#define H_DIM 1152                   // HEADS*F_HID + F_IN
#define OUT_DIM 1536                 // F_OUT + H_DIM
#define NEG 0.01f
#define LN_EPS 1e-5f
#define LOG2E 1.4426950408889634f

typedef __bf16 bf16x8 __attribute__((ext_vector_type(8)));
typedef float  f32x4  __attribute__((ext_vector_type(4)));

static __device__ __forceinline__ unsigned short b16u(float x) {
    union { __bf16 h; unsigned short u; } c; c.h = (__bf16)x; return c.u;
}
static __device__ __forceinline__ unsigned int pk2(float lo, float hi) {
    return (unsigned int)b16u(lo) | ((unsigned int)b16u(hi) << 16);
}

typedef __attribute__((address_space(1))) const unsigned char g1_t;
typedef __attribute__((address_space(3))) unsigned char l3_t;
static __device__ __forceinline__ void gl16(const void* g, void* l) {
    __builtin_amdgcn_global_load_lds((g1_t*)g, (l3_t*)l, 16, 0, 0);
}

// ---------------- kW: WmT[n][k] = bf16(Wm[k][n]) ; WvT[f][k] = bf16(Wv[k][f]) ----
__global__ __launch_bounds__(256) void kW(const float* __restrict__ Wm,
                                          const float* __restrict__ Wv,
                                          unsigned short* __restrict__ WmT,
                                          unsigned short* __restrict__ WvT) {
    __shared__ float tile[32][33];
    const int t = threadIdx.x;
    const int bid = (int)blockIdx.x;
    const float* src; unsigned short* dst;
    int k0, n0, srcld, dstld;
    if (bid < 432) {
        k0 = (bid / 12) * 32; n0 = (bid % 12) * 32;
        src = Wm; dst = WmT; srcld = F_OUT; dstld = H_DIM;
    } else {
        const int e = bid - 432;
        k0 = (e / 3) * 32; n0 = (e % 3) * 32;
        src = Wv; dst = WvT; srcld = F_HID; dstld = F_IN;
    }
#pragma unroll
    for (int p = 0; p < 4; ++p) {
        const int e = t + 256*p, kk = e >> 5, nn = e & 31;
        tile[kk][nn] = src[(size_t)(k0 + kk) * srcld + n0 + nn];
    }
    __syncthreads();
#pragma unroll
    for (int p = 0; p < 4; ++p) {
        const int e = t + 256*p, nn = e >> 5, kk = e & 31;
        dst[(size_t)(n0 + nn) * dstld + k0 + kk] = b16u(tile[kk][nn]);
    }
}

// ---------------- kA: fused LN(X) -> bf16 (LDS) -> V = MFMA -> VT, Q, K ------------
// [PROVEN R12/R16] incl. X fp32 passthrough write to out cols [1152..1536)
__global__ __launch_bounds__(384) void kA(const float* __restrict__ X,
                                          const unsigned short* __restrict__ WvT,
                                          const float* __restrict__ bv,
                                          const float* __restrict__ Wq, const float* __restrict__ bq,
                                          const float* __restrict__ Wk, const float* __restrict__ bk,
                                          unsigned short* __restrict__ VT,
                                          float* __restrict__ Qw, float* __restrict__ Kw,
                                          float* __restrict__ out) {
    __shared__ __align__(16) unsigned short xn[16][392];
    __shared__ float vsh[96][17];
    const int t = threadIdx.x;
    const int bid = (int)blockIdx.x;
    const int swz = (bid & 7) * 64 + (bid >> 3);
    const int i0 = swz * 16;
    const int b = i0 >> 10, i_in = i0 & 1023;
    const int w = t >> 6, l = t & 63, m = l & 15, g = l >> 4;

    if (t < 256) {
        const int r = t >> 4, l16 = t & 15;
        const float4* xrow = (const float4*)(X + (size_t)(i0 + r) * F_IN);
        float4* oX = (float4*)(out + (size_t)(i0 + r) * OUT_DIM + F_OUT + HEADS*F_HID);
        float4 xv[6];
        float s = 0.f, sq = 0.f;
#pragma unroll
        for (int k = 0; k < 6; ++k) {
            xv[k] = xrow[l16 + 16*k];
            oX[l16 + 16*k] = xv[k];
            s  += xv[k].x + xv[k].y + xv[k].z + xv[k].w;
            sq += xv[k].x*xv[k].x + xv[k].y*xv[k].y + xv[k].z*xv[k].z + xv[k].w*xv[k].w;
        }
#pragma unroll
        for (int msk = 1; msk < 16; msk <<= 1) { s += __shfl_xor(s, msk); sq += __shfl_xor(sq, msk); }
        const float mu  = s * (1.f/F_IN);
        const float var = sq * (1.f/F_IN) - mu*mu;
        const float rstd = rsqrtf(var + LN_EPS);
#pragma unroll
        for (int k = 0; k < 6; ++k) {
            ushort4 h4;
            h4.x = b16u((xv[k].x - mu) * rstd);
            h4.y = b16u((xv[k].y - mu) * rstd);
            h4.z = b16u((xv[k].z - mu) * rstd);
            h4.w = b16u((xv[k].w - mu) * rstd);
            *(ushort4*)&xn[r][4*(l16 + 16*k)] = h4;
        }
    }
    __syncthreads();

    const f32x4 z4 = {0.f, 0.f, 0.f, 0.f};
    f32x4 acc = z4;
    const unsigned short* Br = WvT + (size_t)(w*16 + m) * F_IN + g*8;
#pragma unroll
    for (int ks = 0; ks < 12; ++ks) {
        const bf16x8 af  = *(const bf16x8*)&xn[m][ks*32 + g*8];
        const bf16x8 bfr = *(const bf16x8*)(Br + ks*32);
        acc = __builtin_amdgcn_mfma_f32_16x16x32_bf16(af, bfr, acc, 0, 0, 0);
    }
    {
        const int f = w*16 + m;
        const float bvv = bv[f];
#pragma unroll
        for (int r = 0; r < 4; ++r)
            vsh[f][g*4 + r] = acc[r] + bvv;
    }
    __syncthreads();

    {
        const int f = t >> 2, ic = (t & 3) * 4;
        ushort4 h4;
        h4.x = b16u(vsh[f][ic]);   h4.y = b16u(vsh[f][ic+1]);
        h4.z = b16u(vsh[f][ic+2]); h4.w = b16u(vsh[f][ic+3]);
        *(ushort4*)&VT[((size_t)b * F_HID + f) * NN + i_in + ic] = h4;
    }

    if (t < 256) {
        const int i_loc = t & 15, h = (t >> 4) & 7;
        const bool isQ = (t < 128);
        const float* Wx = isQ ? Wq : Wk;
        float a = isQ ? bq[h] : bk[h];
#pragma unroll 8
        for (int f = 0; f < F_HID; ++f)
            a = fmaf(vsh[f][i_loc], Wx[f*HEADS + h], a);
        if (isQ) Qw[(size_t)(i0 + i_loc) * HEADS + h] = a;
        else     Kw[(size_t)(i0 + i_loc) * HEADS + h] = a;
    }
}

// ---------------- kB: 8-wave MFMA attention + fused LN(H) [PROVEN R18 BEST] --------
// K read direct from global in SMAX (L1-resident 2KB chunk, 16-way reuse); Wt/vt
// dbuf, single barrier per chunk, setprio around MFMA, in-block X reduction.
__global__ __launch_bounds__(512, 4) void kB(const float* __restrict__ X,
                                             const unsigned short* __restrict__ VT,
                                             const float* __restrict__ Qw,
                                             const float* __restrict__ Kw,
                                             float* __restrict__ out,
                                             unsigned short* __restrict__ Hn) {
    __shared__ float q_sh[16][8];
    __shared__ __align__(16) unsigned short Wt[2][HEADS][16][64];   // 32 KB (swizzled)
    __shared__ __align__(16) unsigned short vt_sh[2][F_HID][64];    // 24 KB (swizzled)
    __shared__ float lnS[8][16], lnQ2[8][16];
    __shared__ float sxS[16], sx2S[16];
    __shared__ float mu_sh[16], rs_sh[16];

    const int t = threadIdx.x;
    const int bid = (int)blockIdx.x;
    const int swz = (bid & 7) * 64 + (bid >> 3);   // bijective XCD swizzle (512%8==0)
    const int b  = swz >> 6;
    const int i0 = (swz & 63) * 16;
    const int w = t >> 6, l = t & 63, m = l & 15, g = l >> 4;
    const int hp = w >> 1, fh = w & 1;
    const int si = t >> 5, jd = t & 31;

    if (t < 128) ((float*)q_sh)[t] = Qw[((size_t)(b*NN + i0)) * HEADS + t];

    const f32x4 z4 = {0.f, 0.f, 0.f, 0.f};
    f32x4 acc[2][3];
#pragma unroll
    for (int h2 = 0; h2 < 2; ++h2)
#pragma unroll
        for (int fb = 0; fb < 3; ++fb) acc[h2][fb] = z4;

    const size_t vtbase = (size_t)b * F_HID * NN;
    const size_t krow   = (size_t)b * NN;

    // softmax for j-chunk starting at jbase -> Wt[db]; thread (si,jd): j = jbase+2jd,+1
    // K read direct from global: 2 rows x 32 B contiguous, L1-broadcast across si.
#define SMAX(jbase, db)                                                                \
    {                                                                                  \
        const float* kp = Kw + (krow + (jbase) + 2*jd) * HEADS;                        \
        const float4 ka0 = *(const float4*)(kp);                                       \
        const float4 ka1 = *(const float4*)(kp + 4);                                   \
        const float4 kb0 = *(const float4*)(kp + 8);                                   \
        const float4 kb1 = *(const float4*)(kp + 12);                                  \
        const float kE[8] = {ka0.x,ka0.y,ka0.z,ka0.w, ka1.x,ka1.y,ka1.z,ka1.w};        \
        const float kO[8] = {kb0.x,kb0.y,kb0.z,kb0.w, kb1.x,kb1.y,kb1.z,kb1.w};        \
        float p0[8], p1[8];                                                            \
        float s0 = 0.f, s1 = 0.f;                                                      \
        _Pragma("unroll")                                                              \
        for (int h = 0; h < 8; ++h) {                                                  \
            float a0 = q[h] * kE[h]; a0 = fmaxf(a0, NEG*a0);                           \
            float a1 = q[h] * kO[h]; a1 = fmaxf(a1, NEG*a1);                           \
            p0[h] = __builtin_amdgcn_exp2f(a0); s0 += p0[h];                           \
            p1[h] = __builtin_amdgcn_exp2f(a1); s1 += p1[h];                           \
        }                                                                              \
        const float inv0 = 1.f / s0, inv1 = 1.f / s1;                                  \
        char* wbase = (char*)Wt + (db)*16384 + si*128                                  \
                    + ((((jd>>2) ^ (si & 7))) << 4) + ((jd & 3) << 2);                 \
        _Pragma("unroll")                                                              \
        for (int h = 0; h < 8; ++h)                                                    \
            *(unsigned int*)(wbase + h*2048) = pk2(p0[h]*inv0, p1[h]*inv1);            \
    }

    // prologue: stage V(0)
    {
        uint4 vr0, vr1;
        {
            const int f = t >> 3, u = t & 7;
            vr0 = *(const uint4*)(VT + vtbase + (size_t)f*NN + u*8);
        }
        if (t < 256) {
            const int e = t + 512, f2 = e >> 3, u2 = e & 7;
            vr1 = *(const uint4*)(VT + vtbase + (size_t)f2*NN + u2*8);
        }
        {
            const int f = t >> 3, u = t & 7;
            *(uint4*)((char*)vt_sh + f*128 + ((u ^ (f & 7)) << 4)) = vr0;
        }
        if (t < 256) {
            const int e = t + 512, f2 = e >> 3, u2 = e & 7;
            *(uint4*)((char*)vt_sh + f2*128 + ((u2 ^ (f2 & 7)) << 4)) = vr1;
        }
    }
    __syncthreads();

    float q[8];
#pragma unroll
    for (int h = 0; h < 8; ++h) q[h] = q_sh[si][h] * LOG2E;

    SMAX(0, 0);
    __syncthreads();

    for (int c = 0; c < 16; ++c) {
        const int cur = c & 1, nxt = cur ^ 1;

        // phase A: issue next-chunk V reg loads
        uint4 vr0, vr1;
        if (c < 15) {
            const int j0n = (c + 1) * 64;
            {
                const int f = t >> 3, u = t & 7;
                vr0 = *(const uint4*)(VT + vtbase + (size_t)f*NN + j0n + u*8);
            }
            if (t < 256) {
                const int e = t + 512, f2 = e >> 3, u2 = e & 7;
                vr1 = *(const uint4*)(VT + vtbase + (size_t)f2*NN + j0n + u2*8);
            }
        }

        // phase B: softmax(c+1) -> Wt[nxt] (K direct from global)
        if (c < 15) SMAX((c + 1) * 64, nxt);

        // phase C: MFMA chunk c (A = Wt[cur] heads {2hp,2hp+1}, B = vt_sh[cur] fh-half)
        __builtin_amdgcn_s_setprio(1);
#pragma unroll
        for (int kh = 0; kh < 2; ++kh) {
            const int swzu = ((kh*4 + g) ^ (m & 7)) << 4;
            bf16x8 af[2];
#pragma unroll
            for (int h2 = 0; h2 < 2; ++h2)
                af[h2] = *(const bf16x8*)((const char*)Wt + cur*16384
                                          + (hp*2 + h2)*2048 + m*128 + swzu);
            bf16x8 bfr[3];
#pragma unroll
            for (int fb = 0; fb < 3; ++fb) {
                const int f = fh*48 + fb*16 + m;
                bfr[fb] = *(const bf16x8*)((const char*)vt_sh + cur*12288 + f*128 + swzu);
            }
#pragma unroll
            for (int h2 = 0; h2 < 2; ++h2)
#pragma unroll
                for (int fb = 0; fb < 3; ++fb)
                    acc[h2][fb] = __builtin_amdgcn_mfma_f32_16x16x32_bf16(
                        af[h2], bfr[fb], acc[h2][fb], 0, 0, 0);
        }
        __builtin_amdgcn_s_setprio(0);

        // phase D: write staged V regs -> vt_sh[nxt]
        if (c < 15) {
            {
                const int f = t >> 3, u = t & 7;
                *(uint4*)((char*)vt_sh + nxt*12288 + f*128 + ((u ^ (f & 7)) << 4)) = vr0;
            }
            if (t < 256) {
                const int e = t + 512, f2 = e >> 3, u2 = e & 7;
                *(uint4*)((char*)vt_sh + nxt*12288 + f2*128 + ((u2 ^ (f2 & 7)) << 4)) = vr1;
            }
        }
        __syncthreads();   // single barrier: publishes Wt[nxt], vt[nxt]
    }
#undef SMAX

    // ---- fused LN(H): per-row sums from accs ----
    float s[4] = {0,0,0,0}, s2[4] = {0,0,0,0};
#pragma unroll
    for (int h2 = 0; h2 < 2; ++h2)
#pragma unroll
        for (int fb = 0; fb < 3; ++fb)
#pragma unroll
            for (int r = 0; r < 4; ++r) {
                const float v = acc[h2][fb][r];
                s[r] += v; s2[r] += v*v;
            }
#pragma unroll
    for (int msk = 1; msk < 16; msk <<= 1)
#pragma unroll
        for (int r = 0; r < 4; ++r) {
            s[r]  += __shfl_xor(s[r],  msk);
            s2[r] += __shfl_xor(s2[r], msk);
        }
    if (m == 0) {
#pragma unroll
        for (int r = 0; r < 4; ++r) { lnS[w][g*4+r] = s[r]; lnQ2[w][g*4+r] = s2[r]; }
    }

    // X phase: 16 rows x 32 lanes (reads only; passthrough write in kA)
    const int rX = t >> 5, lX = t & 31;
    const size_t xrow = (size_t)(b*NN + i0 + rX);
    const float4* x4 = (const float4*)(X + xrow * F_IN);
    float4 xs[3];
    float sx = 0.f, sx2 = 0.f;
#pragma unroll
    for (int kk = 0; kk < 3; ++kk) {
        xs[kk] = x4[lX + 32*kk];
        sx  += xs[kk].x + xs[kk].y + xs[kk].z + xs[kk].w;
        sx2 += xs[kk].x*xs[kk].x + xs[kk].y*xs[kk].y + xs[kk].z*xs[kk].z + xs[kk].w*xs[kk].w;
    }
#pragma unroll
    for (int msk = 1; msk < 32; msk <<= 1) { sx += __shfl_xor(sx, msk); sx2 += __shfl_xor(sx2, msk); }
    if (lX == 0) { sxS[rX] = sx; sx2S[rX] = sx2; }
    __syncthreads();

    if (t < 16) {
        float tot = sxS[t], tot2 = sx2S[t];
#pragma unroll
        for (int ww = 0; ww < 8; ++ww) { tot += lnS[ww][t]; tot2 += lnQ2[ww][t]; }
        const float muh = tot * (1.f/H_DIM);
        const float varh = tot2 * (1.f/H_DIM) - muh*muh;
        mu_sh[t] = muh; rs_sh[t] = rsqrtf(varh + LN_EPS);
    }
    __syncthreads();

    // Hh: fp32 to out cols [384..1152), bf16-normalized to Hn cols [0..768)
#pragma unroll
    for (int r = 0; r < 4; ++r) {
        const int row = g*4 + r;
        const size_t orow = (size_t)(b*NN + i0 + row);
        const float muh = mu_sh[row], rs = rs_sh[row];
#pragma unroll
        for (int h2 = 0; h2 < 2; ++h2)
#pragma unroll
            for (int fb = 0; fb < 3; ++fb) {
                const int col = (hp*2 + h2)*F_HID + fh*48 + fb*16 + m;
                const float v = acc[h2][fb][r];
                out[orow * OUT_DIM + F_OUT + col] = v;
                Hn[orow * H_DIM + col] = b16u((v - muh) * rs);
            }
    }
    // normalized X -> Hn cols [768..1152)
    {
        const float muh = mu_sh[rX], rs = rs_sh[rX];
#pragma unroll
        for (int kk = 0; kk < 3; ++kk) {
            ushort4 hh;
            hh.x = b16u((xs[kk].x - muh) * rs);
            hh.y = b16u((xs[kk].y - muh) * rs);
            hh.z = b16u((xs[kk].z - muh) * rs);
            hh.w = b16u((xs[kk].w - muh) * rs);
            *(ushort4*)&Hn[xrow * H_DIM + HEADS*F_HID + 4*(lX + 32*kk)] = hh;
        }
    }
}

// ---------------- kC: O = lrelu(Hn @ WmT^T + bm), BM=64 BN=48, grid 1024 [PROVEN R12] ----
__global__ __launch_bounds__(256) void kC(const unsigned short* __restrict__ Hn,
                                          const unsigned short* __restrict__ WmT,
                                          const float* __restrict__ bm,
                                          float* __restrict__ out) {
    __shared__ __align__(16) unsigned short As[2][64*64];
    __shared__ __align__(16) unsigned short Bs[2][48*64];
    const int t = threadIdx.x, w = t >> 6, lane = t & 63, m = lane & 15, g = lane >> 4;
    const int bid = (int)blockIdx.x;
    const int swz = (bid & 7) * 128 + (bid >> 3);
    const int i0 = (swz >> 3) * 64;
    const int n0 = (swz & 7) * 48;

    const f32x4 z4 = {0.f, 0.f, 0.f, 0.f};
    f32x4 acc[3];
#pragma unroll
    for (int ns = 0; ns < 3; ++ns) acc[ns] = z4;

#define KC_STAGE(buf, k0)                                                              \
    {                                                                                  \
        _Pragma("unroll")                                                              \
        for (int p = 0; p < 2; ++p) {                                                  \
            const int e = t + 256*p, row = e >> 3, c16 = e & 7;                        \
            gl16(Hn + (size_t)(i0+row)*H_DIM + (k0) + ((c16 ^ (row&7)) << 3),          \
                 (char*)As[buf] + e*16);                                               \
        }                                                                              \
        {                                                                              \
            const int row = t >> 3, c16 = t & 7;                                       \
            gl16(WmT + (size_t)(n0+row)*H_DIM + (k0) + ((c16 ^ (row&7)) << 3),         \
                 (char*)Bs[buf] + t*16);                                               \
        }                                                                              \
        if (t < 128) {                                                                 \
            const int e = t + 256, row = e >> 3, c16 = e & 7;                          \
            gl16(WmT + (size_t)(n0+row)*H_DIM + (k0) + ((c16 ^ (row&7)) << 3),         \
                 (char*)Bs[buf] + e*16);                                               \
        }                                                                              \
    }

    KC_STAGE(0, 0);
    __syncthreads();

    for (int s = 0; s < 18; ++s) {
        const int cur = s & 1;
        if (s < 17) KC_STAGE(cur ^ 1, (s + 1) * 64);
#pragma unroll
        for (int kh = 0; kh < 2; ++kh) {
            const int kb = kh*64 + g*16;
            const int rowA = w*16 + m;
            const bf16x8 af = *(const bf16x8*)((const char*)As[cur] + rowA*128
                                               + (kb ^ ((rowA&7)<<4)));
#pragma unroll
            for (int ns = 0; ns < 3; ++ns) {
                const int row = ns*16 + m;
                const bf16x8 bf_ = *(const bf16x8*)((const char*)Bs[cur] + row*128
                                                    + (kb ^ ((row&7)<<4)));
                acc[ns] = __builtin_amdgcn_mfma_f32_16x16x32_bf16(af, bf_, acc[ns], 0, 0, 0);
            }
        }
        __syncthreads();
    }
#undef KC_STAGE

#pragma unroll
    for (int ns = 0; ns < 3; ++ns) {
        const int col = n0 + ns*16 + m;
        const float bmv = bm[col];
#pragma unroll
        for (int r = 0; r < 4; ++r) {
            float o = acc[ns][r] + bmv;
            o = fmaxf(o, NEG * o);
            out[(size_t)(i0 + w*16 + g*4 + r) * OUT_DIM + col] = o;
        }
    }
}

extern "C" void kernel_launch(void* const* d_in, const int* in_sizes, int n_in,
                              void* d_out, int out_size, void* d_ws, size_t ws_size,
                              hipStream_t stream) {
    const float* X  = (const float*)d_in[0];
    const float* Wv = (const float*)d_in[1];
    const float* bv = (const float*)d_in[2];
    const float* Wq = (const float*)d_in[3];
    const float* bq = (const float*)d_in[4];
    const float* Wk = (const float*)d_in[5];
    const float* bk = (const float*)d_in[6];
    const float* Wm = (const float*)d_in[7];
    const float* bm = (const float*)d_in[8];
    float* out = (float*)d_out;

    char* p = (char*)d_ws;
    unsigned short* VT  = (unsigned short*)p;                 p += (size_t)BB*F_HID*NN*2;
    float*          Qw  = (float*)p;                          p += (size_t)ROWS*HEADS*4;
    float*          Kw  = (float*)p;                          p += (size_t)ROWS*HEADS*4;
    unsigned short* WmT = (unsigned short*)p;                 p += (size_t)F_OUT*H_DIM*2;
    unsigned short* WvT = (unsigned short*)p;                 p += (size_t)F_HID*F_IN*2;
    unsigned short* Hn  = (unsigned short*)p;                 // ROWS*H_DIM*2 = 18 MB
    (void)ws_size; (void)out_size; (void)n_in; (void)in_sizes;

    kW<<<468, 256, 0, stream>>>(Wm, Wv, WmT, WvT);
    kA<<<ROWS/16, 384, 0, stream>>>(X, WvT, bv, Wq, bq, Wk, bk, VT, Qw, Kw, out);
    kB<<<BB*(NN/16), 512, 0, stream>>>(X, VT, Qw, Kw, out, Hn);
    kC<<<(ROWS/64)*(F_OUT/48), 256, 0, stream>>>(Hn, WmT, bm, out);
}

// Round 22
// 70.610 us; speedup vs baseline: 1.0486x; 1.0033x over previous
//
#include <hip/hip_runtime.h>
#include <hip/hip_bf16.h>
#include <math.h>

#define BB 8
#define NN 1024
#define F_IN 384
#define F_HID 96
#define HEADS 8
#define F_OUT 384
#define ROWS (BB*NN)                 // 8192
#define H_DIM 1152                   // HEADS*F_HID + F_IN
#define OUT_DIM 1536                 // F_OUT + H_DIM
#define NEG 0.01f
#define LN_EPS 1e-5f
#define LOG2E 1.4426950408889634f

typedef __bf16 bf16x8 __attribute__((ext_vector_type(8)));
typedef float  f32x4  __attribute__((ext_vector_type(4)));

static __device__ __forceinline__ unsigned short b16u(float x) {
    union { __bf16 h; unsigned short u; } c; c.h = (__bf16)x; return c.u;
}
static __device__ __forceinline__ unsigned int pk2(float lo, float hi) {
    return (unsigned int)b16u(lo) | ((unsigned int)b16u(hi) << 16);
}

typedef __attribute__((address_space(1))) const unsigned char g1_t;
typedef __attribute__((address_space(3))) unsigned char l3_t;
static __device__ __forceinline__ void gl16(const void* g, void* l) {
    __builtin_amdgcn_global_load_lds((g1_t*)g, (l3_t*)l, 16, 0, 0);
}

// ---------------- kW: WmT[n][k] = bf16(Wm[k][n]) ; WvT[f][k] = bf16(Wv[k][f]) ----
__global__ __launch_bounds__(256) void kW(const float* __restrict__ Wm,
                                          const float* __restrict__ Wv,
                                          unsigned short* __restrict__ WmT,
                                          unsigned short* __restrict__ WvT) {
    __shared__ float tile[32][33];
    const int t = threadIdx.x;
    const int bid = (int)blockIdx.x;
    const float* src; unsigned short* dst;
    int k0, n0, srcld, dstld;
    if (bid < 432) {
        k0 = (bid / 12) * 32; n0 = (bid % 12) * 32;
        src = Wm; dst = WmT; srcld = F_OUT; dstld = H_DIM;
    } else {
        const int e = bid - 432;
        k0 = (e / 3) * 32; n0 = (e % 3) * 32;
        src = Wv; dst = WvT; srcld = F_HID; dstld = F_IN;
    }
#pragma unroll
    for (int p = 0; p < 4; ++p) {
        const int e = t + 256*p, kk = e >> 5, nn = e & 31;
        tile[kk][nn] = src[(size_t)(k0 + kk) * srcld + n0 + nn];
    }
    __syncthreads();
#pragma unroll
    for (int p = 0; p < 4; ++p) {
        const int e = t + 256*p, nn = e >> 5, kk = e & 31;
        dst[(size_t)(n0 + nn) * dstld + k0 + kk] = b16u(tile[kk][nn]);
    }
}

// ---------------- kA: fused LN(X) -> bf16 (LDS) -> V = MFMA -> VT, Q, K ------------
// [PROVEN R12/R16] incl. X fp32 passthrough write to out cols [1152..1536)
__global__ __launch_bounds__(384) void kA(const float* __restrict__ X,
                                          const unsigned short* __restrict__ WvT,
                                          const float* __restrict__ bv,
                                          const float* __restrict__ Wq, const float* __restrict__ bq,
                                          const float* __restrict__ Wk, const float* __restrict__ bk,
                                          unsigned short* __restrict__ VT,
                                          float* __restrict__ Qw, float* __restrict__ Kw,
                                          float* __restrict__ out) {
    __shared__ __align__(16) unsigned short xn[16][392];
    __shared__ float vsh[96][17];
    const int t = threadIdx.x;
    const int bid = (int)blockIdx.x;
    const int swz = (bid & 7) * 64 + (bid >> 3);
    const int i0 = swz * 16;
    const int b = i0 >> 10, i_in = i0 & 1023;
    const int w = t >> 6, l = t & 63, m = l & 15, g = l >> 4;

    if (t < 256) {
        const int r = t >> 4, l16 = t & 15;
        const float4* xrow = (const float4*)(X + (size_t)(i0 + r) * F_IN);
        float4* oX = (float4*)(out + (size_t)(i0 + r) * OUT_DIM + F_OUT + HEADS*F_HID);
        float4 xv[6];
        float s = 0.f, sq = 0.f;
#pragma unroll
        for (int k = 0; k < 6; ++k) {
            xv[k] = xrow[l16 + 16*k];
            oX[l16 + 16*k] = xv[k];
            s  += xv[k].x + xv[k].y + xv[k].z + xv[k].w;
            sq += xv[k].x*xv[k].x + xv[k].y*xv[k].y + xv[k].z*xv[k].z + xv[k].w*xv[k].w;
        }
#pragma unroll
        for (int msk = 1; msk < 16; msk <<= 1) { s += __shfl_xor(s, msk); sq += __shfl_xor(sq, msk); }
        const float mu  = s * (1.f/F_IN);
        const float var = sq * (1.f/F_IN) - mu*mu;
        const float rstd = rsqrtf(var + LN_EPS);
#pragma unroll
        for (int k = 0; k < 6; ++k) {
            ushort4 h4;
            h4.x = b16u((xv[k].x - mu) * rstd);
            h4.y = b16u((xv[k].y - mu) * rstd);
            h4.z = b16u((xv[k].z - mu) * rstd);
            h4.w = b16u((xv[k].w - mu) * rstd);
            *(ushort4*)&xn[r][4*(l16 + 16*k)] = h4;
        }
    }
    __syncthreads();

    const f32x4 z4 = {0.f, 0.f, 0.f, 0.f};
    f32x4 acc = z4;
    const unsigned short* Br = WvT + (size_t)(w*16 + m) * F_IN + g*8;
#pragma unroll
    for (int ks = 0; ks < 12; ++ks) {
        const bf16x8 af  = *(const bf16x8*)&xn[m][ks*32 + g*8];
        const bf16x8 bfr = *(const bf16x8*)(Br + ks*32);
        acc = __builtin_amdgcn_mfma_f32_16x16x32_bf16(af, bfr, acc, 0, 0, 0);
    }
    {
        const int f = w*16 + m;
        const float bvv = bv[f];
#pragma unroll
        for (int r = 0; r < 4; ++r)
            vsh[f][g*4 + r] = acc[r] + bvv;
    }
    __syncthreads();

    {
        const int f = t >> 2, ic = (t & 3) * 4;
        ushort4 h4;
        h4.x = b16u(vsh[f][ic]);   h4.y = b16u(vsh[f][ic+1]);
        h4.z = b16u(vsh[f][ic+2]); h4.w = b16u(vsh[f][ic+3]);
        *(ushort4*)&VT[((size_t)b * F_HID + f) * NN + i_in + ic] = h4;
    }

    if (t < 256) {
        const int i_loc = t & 15, h = (t >> 4) & 7;
        const bool isQ = (t < 128);
        const float* Wx = isQ ? Wq : Wk;
        float a = isQ ? bq[h] : bk[h];
#pragma unroll 8
        for (int f = 0; f < F_HID; ++f)
            a = fmaf(vsh[f][i_loc], Wx[f*HEADS + h], a);
        if (isQ) Qw[(size_t)(i0 + i_loc) * HEADS + h] = a;
        else     Kw[(size_t)(i0 + i_loc) * HEADS + h] = a;
    }
}

// ---------------- kB: 8-wave MFMA attention + fused LN(H) [PROVEN R18 BEST] --------
// K read direct from global in SMAX (L1-resident 2KB chunk, 16-way reuse); Wt/vt
// dbuf, single barrier per chunk, setprio around MFMA, in-block X reduction.
__global__ __launch_bounds__(512, 4) void kB(const float* __restrict__ X,
                                             const unsigned short* __restrict__ VT,
                                             const float* __restrict__ Qw,
                                             const float* __restrict__ Kw,
                                             float* __restrict__ out,
                                             unsigned short* __restrict__ Hn) {
    __shared__ float q_sh[16][8];
    __shared__ __align__(16) unsigned short Wt[2][HEADS][16][64];   // 32 KB (swizzled)
    __shared__ __align__(16) unsigned short vt_sh[2][F_HID][64];    // 24 KB (swizzled)
    __shared__ float lnS[8][16], lnQ2[8][16];
    __shared__ float sxS[16], sx2S[16];
    __shared__ float mu_sh[16], rs_sh[16];

    const int t = threadIdx.x;
    const int bid = (int)blockIdx.x;
    const int swz = (bid & 7) * 64 + (bid >> 3);   // bijective XCD swizzle (512%8==0)
    const int b  = swz >> 6;
    const int i0 = (swz & 63) * 16;
    const int w = t >> 6, l = t & 63, m = l & 15, g = l >> 4;
    const int hp = w >> 1, fh = w & 1;
    const int si = t >> 5, jd = t & 31;

    if (t < 128) ((float*)q_sh)[t] = Qw[((size_t)(b*NN + i0)) * HEADS + t];

    const f32x4 z4 = {0.f, 0.f, 0.f, 0.f};
    f32x4 acc[2][3];
#pragma unroll
    for (int h2 = 0; h2 < 2; ++h2)
#pragma unroll
        for (int fb = 0; fb < 3; ++fb) acc[h2][fb] = z4;

    const size_t vtbase = (size_t)b * F_HID * NN;
    const size_t krow   = (size_t)b * NN;

    // softmax for j-chunk starting at jbase -> Wt[db]; thread (si,jd): j = jbase+2jd,+1
    // K read direct from global: 2 rows x 32 B contiguous, L1-broadcast across si.
#define SMAX(jbase, db)                                                                \
    {                                                                                  \
        const float* kp = Kw + (krow + (jbase) + 2*jd) * HEADS;                        \
        const float4 ka0 = *(const float4*)(kp);                                       \
        const float4 ka1 = *(const float4*)(kp + 4);                                   \
        const float4 kb0 = *(const float4*)(kp + 8);                                   \
        const float4 kb1 = *(const float4*)(kp + 12);                                  \
        const float kE[8] = {ka0.x,ka0.y,ka0.z,ka0.w, ka1.x,ka1.y,ka1.z,ka1.w};        \
        const float kO[8] = {kb0.x,kb0.y,kb0.z,kb0.w, kb1.x,kb1.y,kb1.z,kb1.w};        \
        float p0[8], p1[8];                                                            \
        float s0 = 0.f, s1 = 0.f;                                                      \
        _Pragma("unroll")                                                              \
        for (int h = 0; h < 8; ++h) {                                                  \
            float a0 = q[h] * kE[h]; a0 = fmaxf(a0, NEG*a0);                           \
            float a1 = q[h] * kO[h]; a1 = fmaxf(a1, NEG*a1);                           \
            p0[h] = __builtin_amdgcn_exp2f(a0); s0 += p0[h];                           \
            p1[h] = __builtin_amdgcn_exp2f(a1); s1 += p1[h];                           \
        }                                                                              \
        const float inv0 = 1.f / s0, inv1 = 1.f / s1;                                  \
        char* wbase = (char*)Wt + (db)*16384 + si*128                                  \
                    + ((((jd>>2) ^ (si & 7))) << 4) + ((jd & 3) << 2);                 \
        _Pragma("unroll")                                                              \
        for (int h = 0; h < 8; ++h)                                                    \
            *(unsigned int*)(wbase + h*2048) = pk2(p0[h]*inv0, p1[h]*inv1);            \
    }

    // prologue: stage V(0)
    {
        uint4 vr0, vr1;
        {
            const int f = t >> 3, u = t & 7;
            vr0 = *(const uint4*)(VT + vtbase + (size_t)f*NN + u*8);
        }
        if (t < 256) {
            const int e = t + 512, f2 = e >> 3, u2 = e & 7;
            vr1 = *(const uint4*)(VT + vtbase + (size_t)f2*NN + u2*8);
        }
        {
            const int f = t >> 3, u = t & 7;
            *(uint4*)((char*)vt_sh + f*128 + ((u ^ (f & 7)) << 4)) = vr0;
        }
        if (t < 256) {
            const int e = t + 512, f2 = e >> 3, u2 = e & 7;
            *(uint4*)((char*)vt_sh + f2*128 + ((u2 ^ (f2 & 7)) << 4)) = vr1;
        }
    }
    __syncthreads();

    float q[8];
#pragma unroll
    for (int h = 0; h < 8; ++h) q[h] = q_sh[si][h] * LOG2E;

    SMAX(0, 0);
    __syncthreads();

    for (int c = 0; c < 16; ++c) {
        const int cur = c & 1, nxt = cur ^ 1;

        // phase A: issue next-chunk V reg loads
        uint4 vr0, vr1;
        if (c < 15) {
            const int j0n = (c + 1) * 64;
            {
                const int f = t >> 3, u = t & 7;
                vr0 = *(const uint4*)(VT + vtbase + (size_t)f*NN + j0n + u*8);
            }
            if (t < 256) {
                const int e = t + 512, f2 = e >> 3, u2 = e & 7;
                vr1 = *(const uint4*)(VT + vtbase + (size_t)f2*NN + j0n + u2*8);
            }
        }

        // phase B: softmax(c+1) -> Wt[nxt] (K direct from global)
        if (c < 15) SMAX((c + 1) * 64, nxt);

        // phase C: MFMA chunk c (A = Wt[cur] heads {2hp,2hp+1}, B = vt_sh[cur] fh-half)
        __builtin_amdgcn_s_setprio(1);
#pragma unroll
        for (int kh = 0; kh < 2; ++kh) {
            const int swzu = ((kh*4 + g) ^ (m & 7)) << 4;
            bf16x8 af[2];
#pragma unroll
            for (int h2 = 0; h2 < 2; ++h2)
                af[h2] = *(const bf16x8*)((const char*)Wt + cur*16384
                                          + (hp*2 + h2)*2048 + m*128 + swzu);
            bf16x8 bfr[3];
#pragma unroll
            for (int fb = 0; fb < 3; ++fb) {
                const int f = fh*48 + fb*16 + m;
                bfr[fb] = *(const bf16x8*)((const char*)vt_sh + cur*12288 + f*128 + swzu);
            }
#pragma unroll
            for (int h2 = 0; h2 < 2; ++h2)
#pragma unroll
                for (int fb = 0; fb < 3; ++fb)
                    acc[h2][fb] = __builtin_amdgcn_mfma_f32_16x16x32_bf16(
                        af[h2], bfr[fb], acc[h2][fb], 0, 0, 0);
        }
        __builtin_amdgcn_s_setprio(0);

        // phase D: write staged V regs -> vt_sh[nxt]
        if (c < 15) {
            {
                const int f = t >> 3, u = t & 7;
                *(uint4*)((char*)vt_sh + nxt*12288 + f*128 + ((u ^ (f & 7)) << 4)) = vr0;
            }
            if (t < 256) {
                const int e = t + 512, f2 = e >> 3, u2 = e & 7;
                *(uint4*)((char*)vt_sh + nxt*12288 + f2*128 + ((u2 ^ (f2 & 7)) << 4)) = vr1;
            }
        }
        __syncthreads();   // single barrier: publishes Wt[nxt], vt[nxt]
    }
#undef SMAX

    // ---- fused LN(H): per-row sums from accs ----
    float s[4] = {0,0,0,0}, s2[4] = {0,0,0,0};
#pragma unroll
    for (int h2 = 0; h2 < 2; ++h2)
#pragma unroll
        for (int fb = 0; fb < 3; ++fb)
#pragma unroll
            for (int r = 0; r < 4; ++r) {
                const float v = acc[h2][fb][r];
                s[r] += v; s2[r] += v*v;
            }
#pragma unroll
    for (int msk = 1; msk < 16; msk <<= 1)
#pragma unroll
        for (int r = 0; r < 4; ++r) {
            s[r]  += __shfl_xor(s[r],  msk);
            s2[r] += __shfl_xor(s2[r], msk);
        }
    if (m == 0) {
#pragma unroll
        for (int r = 0; r < 4; ++r) { lnS[w][g*4+r] = s[r]; lnQ2[w][g*4+r] = s2[r]; }
    }

    // X phase: 16 rows x 32 lanes (reads only; passthrough write in kA)
    const int rX = t >> 5, lX = t & 31;
    const size_t xrow = (size_t)(b*NN + i0 + rX);
    const float4* x4 = (const float4*)(X + xrow * F_IN);
    float4 xs[3];
    float sx = 0.f, sx2 = 0.f;
#pragma unroll
    for (int kk = 0; kk < 3; ++kk) {
        xs[kk] = x4[lX + 32*kk];
        sx  += xs[kk].x + xs[kk].y + xs[kk].z + xs[kk].w;
        sx2 += xs[kk].x*xs[kk].x + xs[kk].y*xs[kk].y + xs[kk].z*xs[kk].z + xs[kk].w*xs[kk].w;
    }
#pragma unroll
    for (int msk = 1; msk < 32; msk <<= 1) { sx += __shfl_xor(sx, msk); sx2 += __shfl_xor(sx2, msk); }
    if (lX == 0) { sxS[rX] = sx; sx2S[rX] = sx2; }
    __syncthreads();

    if (t < 16) {
        float tot = sxS[t], tot2 = sx2S[t];
#pragma unroll
        for (int ww = 0; ww < 8; ++ww) { tot += lnS[ww][t]; tot2 += lnQ2[ww][t]; }
        const float muh = tot * (1.f/H_DIM);
        const float varh = tot2 * (1.f/H_DIM) - muh*muh;
        mu_sh[t] = muh; rs_sh[t] = rsqrtf(varh + LN_EPS);
    }
    __syncthreads();

    // Hh: fp32 to out cols [384..1152), bf16-normalized to Hn cols [0..768)
#pragma unroll
    for (int r = 0; r < 4; ++r) {
        const int row = g*4 + r;
        const size_t orow = (size_t)(b*NN + i0 + row);
        const float muh = mu_sh[row], rs = rs_sh[row];
#pragma unroll
        for (int h2 = 0; h2 < 2; ++h2)
#pragma unroll
            for (int fb = 0; fb < 3; ++fb) {
                const int col = (hp*2 + h2)*F_HID + fh*48 + fb*16 + m;
                const float v = acc[h2][fb][r];
                out[orow * OUT_DIM + F_OUT + col] = v;
                Hn[orow * H_DIM + col] = b16u((v - muh) * rs);
            }
    }
    // normalized X -> Hn cols [768..1152)
    {
        const float muh = mu_sh[rX], rs = rs_sh[rX];
#pragma unroll
        for (int kk = 0; kk < 3; ++kk) {
            ushort4 hh;
            hh.x = b16u((xs[kk].x - muh) * rs);
            hh.y = b16u((xs[kk].y - muh) * rs);
            hh.z = b16u((xs[kk].z - muh) * rs);
            hh.w = b16u((xs[kk].w - muh) * rs);
            *(ushort4*)&Hn[xrow * H_DIM + HEADS*F_HID + 4*(lX + 32*kk)] = hh;
        }
    }
}

// ---------------- kC: O = lrelu(Hn @ WmT^T + bm), BM=64 BN=48, grid 1024 [PROVEN R12] ----
__global__ __launch_bounds__(256) void kC(const unsigned short* __restrict__ Hn,
                                          const unsigned short* __restrict__ WmT,
                                          const float* __restrict__ bm,
                                          float* __restrict__ out) {
    __shared__ __align__(16) unsigned short As[2][64*64];
    __shared__ __align__(16) unsigned short Bs[2][48*64];
    const int t = threadIdx.x, w = t >> 6, lane = t & 63, m = lane & 15, g = lane >> 4;
    const int bid = (int)blockIdx.x;
    const int swz = (bid & 7) * 128 + (bid >> 3);
    const int i0 = (swz >> 3) * 64;
    const int n0 = (swz & 7) * 48;

    const f32x4 z4 = {0.f, 0.f, 0.f, 0.f};
    f32x4 acc[3];
#pragma unroll
    for (int ns = 0; ns < 3; ++ns) acc[ns] = z4;

#define KC_STAGE(buf, k0)                                                              \
    {                                                                                  \
        _Pragma("unroll")                                                              \
        for (int p = 0; p < 2; ++p) {                                                  \
            const int e = t + 256*p, row = e >> 3, c16 = e & 7;                        \
            gl16(Hn + (size_t)(i0+row)*H_DIM + (k0) + ((c16 ^ (row&7)) << 3),          \
                 (char*)As[buf] + e*16);                                               \
        }                                                                              \
        {                                                                              \
            const int row = t >> 3, c16 = t & 7;                                       \
            gl16(WmT + (size_t)(n0+row)*H_DIM + (k0) + ((c16 ^ (row&7)) << 3),         \
                 (char*)Bs[buf] + t*16);                                               \
        }                                                                              \
        if (t < 128) {                                                                 \
            const int e = t + 256, row = e >> 3, c16 = e & 7;                          \
            gl16(WmT + (size_t)(n0+row)*H_DIM + (k0) + ((c16 ^ (row&7)) << 3),         \
                 (char*)Bs[buf] + e*16);                                               \
        }                                                                              \
    }

    KC_STAGE(0, 0);
    __syncthreads();

    for (int s = 0; s < 18; ++s) {
        const int cur = s & 1;
        if (s < 17) KC_STAGE(cur ^ 1, (s + 1) * 64);
#pragma unroll
        for (int kh = 0; kh < 2; ++kh) {
            const int kb = kh*64 + g*16;
            const int rowA = w*16 + m;
            const bf16x8 af = *(const bf16x8*)((const char*)As[cur] + rowA*128
                                               + (kb ^ ((rowA&7)<<4)));
#pragma unroll
            for (int ns = 0; ns < 3; ++ns) {
                const int row = ns*16 + m;
                const bf16x8 bf_ = *(const bf16x8*)((const char*)Bs[cur] + row*128
                                                    + (kb ^ ((row&7)<<4)));
                acc[ns] = __builtin_amdgcn_mfma_f32_16x16x32_bf16(af, bf_, acc[ns], 0, 0, 0);
            }
        }
        __syncthreads();
    }
#undef KC_STAGE

#pragma unroll
    for (int ns = 0; ns < 3; ++ns) {
        const int col = n0 + ns*16 + m;
        const float bmv = bm[col];
#pragma unroll
        for (int r = 0; r < 4; ++r) {
            float o = acc[ns][r] + bmv;
            o = fmaxf(o, NEG * o);
            out[(size_t)(i0 + w*16 + g*4 + r) * OUT_DIM + col] = o;
        }
    }
}

extern "C" void kernel_launch(void* const* d_in, const int* in_sizes, int n_in,
                              void* d_out, int out_size, void* d_ws, size_t ws_size,
                              hipStream_t stream) {
    const float* X  = (const float*)d_in[0];
    const float* Wv = (const float*)d_in[1];
    const float* bv = (const float*)d_in[2];
    const float* Wq = (const float*)d_in[3];
    const float* bq = (const float*)d_in[4];
    const float* Wk = (const float*)d_in[5];
    const float* bk = (const float*)d_in[6];
    const float* Wm = (const float*)d_in[7];
    const float* bm = (const float*)d_in[8];
    float* out = (float*)d_out;

    char* p = (char*)d_ws;
    unsigned short* VT  = (unsigned short*)p;                 p += (size_t)BB*F_HID*NN*2;
    float*          Qw  = (float*)p;                          p += (size_t)ROWS*HEADS*4;
    float*          Kw  = (float*)p;                          p += (size_t)ROWS*HEADS*4;
    unsigned short* WmT = (unsigned short*)p;                 p += (size_t)F_OUT*H_DIM*2;
    unsigned short* WvT = (unsigned short*)p;                 p += (size_t)F_HID*F_IN*2;
    unsigned short* Hn  = (unsigned short*)p;                 // ROWS*H_DIM*2 = 18 MB
    (void)ws_size; (void)out_size; (void)n_in; (void)in_sizes;

    kW<<<468, 256, 0, stream>>>(Wm, Wv, WmT, WvT);
    kA<<<ROWS/16, 384, 0, stream>>>(X, WvT, bv, Wq, bq, Wk, bk, VT, Qw, Kw, out);
    kB<<<BB*(NN/16), 512, 0, stream>>>(X, VT, Qw, Kw, out, Hn);
    kC<<<(ROWS/64)*(F_OUT/48), 256, 0, stream>>>(Hn, WmT, bm, out);
}